// Round 1
// baseline (555.333 us; speedup 1.0000x reference)
//
#include <hip/hip_runtime.h>
#include <hip/hip_bf16.h>

#define DIM   1024
#define NSEQ  1024
#define BATCH 2
#define NHEAD 16
#define DH    64

// ---------------------------------------------------------------------------
// Densify block-circulant weights: Wd[r][c] = w[p][q][(a-b)&7]
// r = p*8+a, c = q*8+b.  4 matrices (q,k,v,o) selected by blockIdx.z.
// ---------------------------------------------------------------------------
__global__ __launch_bounds__(256) void densify_kernel(
    const float* __restrict__ wq, const float* __restrict__ wk,
    const float* __restrict__ wv, const float* __restrict__ wo,
    float* __restrict__ Wd) {
  const int z = blockIdx.z;
  const float* w = (z == 0) ? wq : (z == 1) ? wk : (z == 2) ? wv : wo;
  float* out = Wd + (size_t)z * DIM * DIM;
  const int idx = blockIdx.x * 256 + threadIdx.x;   // 0 .. 1024*1024-1
  const int r = idx >> 10, c = idx & 1023;
  const int p = r >> 3, a = r & 7;
  const int q = c >> 3, b = c & 7;
  out[idx] = w[(p * 128 + q) * 8 + ((a - b) & 7)];
}

// ---------------------------------------------------------------------------
// GEMM (NT) + bias:  C[m][n] = sum_k A[m][k] * W[n][k] + bias[n]
// A: [2048][1024] row-major, W: dense [1024][1024] row-major.
// 64x64 tile, BK=16, 256 threads, 4x4 micro-tile per thread.
// gridDim.z selects (bias, C) and the z-th dense weight matrix.
// ---------------------------------------------------------------------------
__global__ __launch_bounds__(256) void gemm_nt_bias(
    const float* __restrict__ A,
    const float* __restrict__ Wdbase,
    const float* __restrict__ b0, const float* __restrict__ b1,
    const float* __restrict__ b2,
    float* __restrict__ C0, float* __restrict__ C1, float* __restrict__ C2) {
  const int z = blockIdx.z;
  const float* W    = Wdbase + (size_t)z * DIM * DIM;
  const float* bias = (z == 0) ? b0 : (z == 1) ? b1 : b2;
  float* C          = (z == 0) ? C0 : (z == 1) ? C1 : C2;

  const int tid = threadIdx.x;
  const int tx = tid & 15, ty = tid >> 4;
  const int nb = blockIdx.x * 64;
  const int mb = blockIdx.y * 64;

  __shared__ float As[16][65];   // [k][m], pad 65 -> conflict-free stores
  __shared__ float Bs[16][65];   // [k][n]

  float c[4][4] = {};

  const int lrow = tid >> 2;          // 0..63
  const int lk   = (tid & 3) * 4;     // 0,4,8,12
  const float* Ap = A + (size_t)(mb + lrow) * DIM + lk;
  const float* Wp = W + (size_t)(nb + lrow) * DIM + lk;

  for (int k0 = 0; k0 < DIM; k0 += 16) {
    const float4 av = *(const float4*)(Ap + k0);
    const float4 wv = *(const float4*)(Wp + k0);
    __syncthreads();
    As[lk + 0][lrow] = av.x; As[lk + 1][lrow] = av.y;
    As[lk + 2][lrow] = av.z; As[lk + 3][lrow] = av.w;
    Bs[lk + 0][lrow] = wv.x; Bs[lk + 1][lrow] = wv.y;
    Bs[lk + 2][lrow] = wv.z; Bs[lk + 3][lrow] = wv.w;
    __syncthreads();
#pragma unroll
    for (int kk = 0; kk < 16; ++kk) {
      float a[4], bb[4];
#pragma unroll
      for (int i = 0; i < 4; ++i) a[i] = As[kk][ty * 4 + i];
#pragma unroll
      for (int j = 0; j < 4; ++j) bb[j] = Bs[kk][tx * 4 + j];
#pragma unroll
      for (int i = 0; i < 4; ++i)
#pragma unroll
        for (int j = 0; j < 4; ++j)
          c[i][j] = fmaf(a[i], bb[j], c[i][j]);
    }
  }

  const float4 bv = *(const float4*)(bias + nb + tx * 4);
  const float bb4[4] = {bv.x, bv.y, bv.z, bv.w};
#pragma unroll
  for (int i = 0; i < 4; ++i) {
    float4 o;
    o.x = c[i][0] + bb4[0]; o.y = c[i][1] + bb4[1];
    o.z = c[i][2] + bb4[2]; o.w = c[i][3] + bb4[3];
    *(float4*)(C + (size_t)(mb + ty * 4 + i) * DIM + nb + tx * 4) = o;
  }
}

// ---------------------------------------------------------------------------
// Causal flash attention, fp32.
// Block: 256 threads = 64 queries x 4 threads (each owns 16 of dh=64 dims).
// Grid: (qtile=16, head=16, batch=2).  K/V staged 64 rows at a time in LDS.
// ---------------------------------------------------------------------------
__global__ __launch_bounds__(256) void attn_kernel(
    const float* __restrict__ Q, const float* __restrict__ Kg,
    const float* __restrict__ Vg, float* __restrict__ O) {
  const int qt = blockIdx.x;      // 0..15
  const int h  = blockIdx.y;      // 0..15
  const int b  = blockIdx.z;      // 0..1
  const int tid = threadIdx.x;
  const int qi = tid >> 2;        // 0..63 (query within tile)
  const int g  = tid & 3;         // dim-group (16 dims each)
  const int n  = qt * 64 + qi;    // global query row

  __shared__ float Kt[64][64];
  __shared__ float Vt[64][64];

  float q[16], acc[16];
  {
    const float* Qp = Q + ((size_t)(b * NSEQ + n)) * DIM + h * DH + g * 16;
#pragma unroll
    for (int j4 = 0; j4 < 4; ++j4) {
      const float4 v = *(const float4*)(Qp + j4 * 4);
      q[j4 * 4 + 0] = v.x * 0.125f; q[j4 * 4 + 1] = v.y * 0.125f;
      q[j4 * 4 + 2] = v.z * 0.125f; q[j4 * 4 + 3] = v.w * 0.125f;
    }
  }
#pragma unroll
  for (int j = 0; j < 16; ++j) acc[j] = 0.f;
  float m_run = -1e30f, l_run = 0.f;

  const size_t khbase = ((size_t)b * NSEQ) * DIM + (size_t)h * DH;

  for (int t = 0; t <= qt; ++t) {
    __syncthreads();
#pragma unroll
    for (int it = 0; it < 4; ++it) {
      const int f = tid + 256 * it;       // 0..1023
      const int row = f >> 4;
      const int c4  = (f & 15) * 4;
      const size_t gaddr = khbase + (size_t)(t * 64 + row) * DIM + c4;
      *(float4*)&Kt[row][c4] = *(const float4*)(Kg + gaddr);
      *(float4*)&Vt[row][c4] = *(const float4*)(Vg + gaddr);
    }
    __syncthreads();

    for (int mc = 0; mc < 4; ++mc) {
      const int mbase = t * 64 + mc * 16;
      float p[16];
      float cmax = -1e30f;
#pragma unroll
      for (int mm = 0; mm < 16; ++mm) {
        float s = 0.f;
#pragma unroll
        for (int j = 0; j < 16; ++j)
          s = fmaf(q[j], Kt[mc * 16 + mm][g * 16 + j], s);
        s += __shfl_xor(s, 1);
        s += __shfl_xor(s, 2);
        s = (mbase + mm <= n) ? s : -1e30f;
        p[mm] = s;
        cmax = fmaxf(cmax, s);
      }
      const float m_new  = fmaxf(m_run, cmax);
      const float fscale = __expf(m_run - m_new);
      float psum = 0.f;
#pragma unroll
      for (int mm = 0; mm < 16; ++mm) {
        p[mm] = __expf(p[mm] - m_new);
        psum += p[mm];
      }
      l_run = l_run * fscale + psum;
#pragma unroll
      for (int j = 0; j < 16; ++j) acc[j] *= fscale;
#pragma unroll
      for (int mm = 0; mm < 16; ++mm)
#pragma unroll
        for (int j = 0; j < 16; ++j)
          acc[j] = fmaf(p[mm], Vt[mc * 16 + mm][g * 16 + j], acc[j]);
      m_run = m_new;
    }
  }

  const float inv = 1.f / l_run;
  float* Op = O + ((size_t)(b * NSEQ + n)) * DIM + h * DH + g * 16;
#pragma unroll
  for (int j4 = 0; j4 < 4; ++j4) {
    float4 v;
    v.x = acc[j4 * 4 + 0] * inv; v.y = acc[j4 * 4 + 1] * inv;
    v.z = acc[j4 * 4 + 2] * inv; v.w = acc[j4 * 4 + 3] * inv;
    *(float4*)(Op + j4 * 4) = v;
  }
}

// ---------------------------------------------------------------------------
extern "C" void kernel_launch(void* const* d_in, const int* in_sizes, int n_in,
                              void* d_out, int out_size, void* d_ws, size_t ws_size,
                              hipStream_t stream) {
  const float* x  = (const float*)d_in[0];
  // d_in[1] = causal mask (ignored; mask is m > n analytically)
  const float* wq = (const float*)d_in[2];
  const float* bq = (const float*)d_in[3];
  const float* wk = (const float*)d_in[4];
  const float* bk = (const float*)d_in[5];
  const float* wv = (const float*)d_in[6];
  const float* bv = (const float*)d_in[7];
  const float* wo = (const float*)d_in[8];
  const float* bo = (const float*)d_in[9];
  float* out = (float*)d_out;

  char* ws = (char*)d_ws;
  float* Wd = (float*)(ws);                         // 4 x 4MB dense weights
  float* Qb = (float*)(ws + ((size_t)16 << 20));    // 8MB
  float* Kb = (float*)(ws + ((size_t)24 << 20));    // 8MB
  float* Vb = (float*)(ws + ((size_t)32 << 20));    // 8MB
  float* AO = (float*)(ws + ((size_t)40 << 20));    // 8MB

  // 1) densify the 4 circulant weight matrices
  densify_kernel<<<dim3(4096, 1, 4), 256, 0, stream>>>(wq, wk, wv, wo, Wd);

  // 2) Q/K/V projections (one launch, z = 0/1/2)
  gemm_nt_bias<<<dim3(16, 32, 3), 256, 0, stream>>>(
      x, Wd, bq, bk, bv, Qb, Kb, Vb);

  // 3) causal attention
  attn_kernel<<<dim3(16, 16, 2), 256, 0, stream>>>(Qb, Kb, Vb, AO);

  // 4) output projection (z = 0 only, weight index 3)
  gemm_nt_bias<<<dim3(16, 32, 1), 256, 0, stream>>>(
      AO, Wd + (size_t)3 * DIM * DIM, bo, bo, bo, out, out, out);
}

// Round 3
// 261.518 us; speedup vs baseline: 2.1235x; 2.1235x over previous
//
#include <hip/hip_runtime.h>
#include <hip/hip_bf16.h>

#define DIM   1024
#define NSEQ  1024
#define BATCH 2
#define NHEAD 16
#define DH    64

typedef unsigned short u16;
typedef __attribute__((ext_vector_type(8))) short  short8;
typedef __attribute__((ext_vector_type(4))) float  f32x4;
typedef __attribute__((ext_vector_type(8))) unsigned short u16x8;
typedef __attribute__((ext_vector_type(4))) unsigned short u16x4;

__device__ __forceinline__ u16 f2bf(float f) {
  union { float f; unsigned u; } v; v.f = f;
  unsigned r = v.u + 0x7FFFu + ((v.u >> 16) & 1u);   // RNE
  return (u16)(r >> 16);
}

// ---------------------------------------------------------------------------
// Densify block-circulant weights -> bf16 dense: Wd[r][c] = w[p][q][(a-b)&7]
// ---------------------------------------------------------------------------
__global__ __launch_bounds__(256) void densify_bf16(
    const float* __restrict__ wq, const float* __restrict__ wk,
    const float* __restrict__ wv, const float* __restrict__ wo,
    u16* __restrict__ Wd) {
  const int z = blockIdx.z;
  const float* w = (z == 0) ? wq : (z == 1) ? wk : (z == 2) ? wv : wo;
  u16* out = Wd + (size_t)z * DIM * DIM;
  const int idx = blockIdx.x * 256 + threadIdx.x;
  const int r = idx >> 10, c = idx & 1023;
  const int p = r >> 3, a = r & 7;
  const int q = c >> 3, b = c & 7;
  out[idx] = f2bf(w[(p * 128 + q) * 8 + ((a - b) & 7)]);
}

// ---------------------------------------------------------------------------
// fp32 -> bf16 conversion, 8 elements/thread
// ---------------------------------------------------------------------------
__global__ __launch_bounds__(256) void cvt_bf16(
    const float* __restrict__ in, u16* __restrict__ out) {
  const int i = blockIdx.x * 256 + threadIdx.x;
  const float4 a = ((const float4*)in)[2 * i];
  const float4 b = ((const float4*)in)[2 * i + 1];
  u16x8 o;
  o[0] = f2bf(a.x); o[1] = f2bf(a.y); o[2] = f2bf(a.z); o[3] = f2bf(a.w);
  o[4] = f2bf(b.x); o[5] = f2bf(b.y); o[6] = f2bf(b.z); o[7] = f2bf(b.w);
  ((u16x8*)out)[i] = o;
}

// ---------------------------------------------------------------------------
// bf16 MFMA GEMM (NT) + bias: C[m][n] = sum_k A[m][k]*W[n][k] + bias[n]
// A: [M][1024] bf16, W: [1024][1024] bf16 (z-th matrix), C fp32.
// m97 structure: 128x128 tile, BK=32, 256 thr (4 waves, 2x2), 4x4 frags/wave,
// global_load_lds width-16 staging, single LDS buffer, 2 barriers/K-step.
// ---------------------------------------------------------------------------
__global__ __launch_bounds__(256) void gemm_bf16_nt(
    const u16* __restrict__ A, const u16* __restrict__ Wbase,
    const float* __restrict__ b0, const float* __restrict__ b1,
    const float* __restrict__ b2,
    float* __restrict__ C0, float* __restrict__ C1, float* __restrict__ C2) {
  const int z = blockIdx.z;
  const u16* W      = Wbase + (size_t)z * DIM * DIM;
  const float* bias = (z == 0) ? b0 : (z == 1) ? b1 : b2;
  float* C          = (z == 0) ? C0 : (z == 1) ? C1 : C2;

  __shared__ u16 As[128 * 32];
  __shared__ u16 Bs[128 * 32];

  const int tid  = threadIdx.x;
  const int w    = tid >> 6, lane = tid & 63;
  const int mb   = blockIdx.y * 128, nb = blockIdx.x * 128;

  f32x4 acc[4][4] = {};

  const int m0 = (w >> 1) * 64, n0 = (w & 1) * 64;
  const int lr = lane & 15, lk = (lane >> 4) * 8;

  // staging: wave w covers chunk-blocks {2w, 2w+1}; chunk = cb*64 + lane
  // chunk c -> row c/4, u16 col (c&3)*8 ; LDS byte addr = c*16 (linear)
  const int cb = w * 2;
  const int c0 = cb * 64 + lane;
  const int c1 = c0 + 64;
  const int row0 = c0 >> 2, kc0 = (c0 & 3) * 8;
  const int row1 = c1 >> 2, kc1 = (c1 & 3) * 8;

  for (int k0 = 0; k0 < DIM; k0 += 32) {
    __syncthreads();   // previous K-step's reads done before overwrite
    __builtin_amdgcn_global_load_lds(
        (const __attribute__((address_space(1))) void*)(A + (size_t)(mb + row0) * DIM + k0 + kc0),
        (__attribute__((address_space(3))) void*)(As + (size_t)cb * 512), 16, 0, 0);
    __builtin_amdgcn_global_load_lds(
        (const __attribute__((address_space(1))) void*)(W + (size_t)(nb + row0) * DIM + k0 + kc0),
        (__attribute__((address_space(3))) void*)(Bs + (size_t)cb * 512), 16, 0, 0);
    __builtin_amdgcn_global_load_lds(
        (const __attribute__((address_space(1))) void*)(A + (size_t)(mb + row1) * DIM + k0 + kc1),
        (__attribute__((address_space(3))) void*)(As + (size_t)(cb + 1) * 512), 16, 0, 0);
    __builtin_amdgcn_global_load_lds(
        (const __attribute__((address_space(1))) void*)(W + (size_t)(nb + row1) * DIM + k0 + kc1),
        (__attribute__((address_space(3))) void*)(Bs + (size_t)(cb + 1) * 512), 16, 0, 0);
    __syncthreads();   // drains vmcnt(0): tiles resident

    short8 a[4], b[4];
#pragma unroll
    for (int mi = 0; mi < 4; ++mi)
      a[mi] = *(const short8*)&As[(m0 + mi * 16 + lr) * 32 + lk];
#pragma unroll
    for (int ni = 0; ni < 4; ++ni)
      b[ni] = *(const short8*)&Bs[(n0 + ni * 16 + lr) * 32 + lk];
#pragma unroll
    for (int mi = 0; mi < 4; ++mi)
#pragma unroll
      for (int ni = 0; ni < 4; ++ni)
        acc[mi][ni] = __builtin_amdgcn_mfma_f32_16x16x32_bf16(
            a[mi], b[ni], acc[mi][ni], 0, 0, 0);
  }

  // epilogue: C/D layout col = lane&15, row = (lane>>4)*4 + j   [m89/m91]
  const int col = lane & 15, rq = (lane >> 4) * 4;
#pragma unroll
  for (int ni = 0; ni < 4; ++ni) {
    const int gc = nb + n0 + ni * 16 + col;
    const float bv = bias[gc];
#pragma unroll
    for (int mi = 0; mi < 4; ++mi) {
      const size_t rbase = (size_t)(mb + m0 + mi * 16 + rq) * DIM + gc;
#pragma unroll
      for (int j = 0; j < 4; ++j)
        C[rbase + (size_t)j * DIM] = acc[mi][ni][j] + bv;
    }
  }
}

// ---------------------------------------------------------------------------
// Causal flash attention, fp32 compute, bf16 output (feeds O-projection GEMM).
// Block: 256 threads = 64 queries x 4 thread-groups (16 dims each).
// ---------------------------------------------------------------------------
__global__ __launch_bounds__(256) void attn_kernel(
    const float* __restrict__ Q, const float* __restrict__ Kg,
    const float* __restrict__ Vg, u16* __restrict__ O) {
  const int qt = blockIdx.x;
  const int h  = blockIdx.y;
  const int b  = blockIdx.z;
  const int tid = threadIdx.x;
  const int qi = tid >> 2;
  const int g  = tid & 3;
  const int n  = qt * 64 + qi;

  __shared__ float Kt[64][64];
  __shared__ float Vt[64][64];

  float q[16], acc[16];
  {
    const float* Qp = Q + ((size_t)(b * NSEQ + n)) * DIM + h * DH + g * 16;
#pragma unroll
    for (int j4 = 0; j4 < 4; ++j4) {
      const float4 v = *(const float4*)(Qp + j4 * 4);
      q[j4 * 4 + 0] = v.x * 0.125f; q[j4 * 4 + 1] = v.y * 0.125f;
      q[j4 * 4 + 2] = v.z * 0.125f; q[j4 * 4 + 3] = v.w * 0.125f;
    }
  }
#pragma unroll
  for (int j = 0; j < 16; ++j) acc[j] = 0.f;
  float m_run = -1e30f, l_run = 0.f;

  const size_t khbase = ((size_t)b * NSEQ) * DIM + (size_t)h * DH;

  for (int t = 0; t <= qt; ++t) {
    __syncthreads();
#pragma unroll
    for (int it = 0; it < 4; ++it) {
      const int f = tid + 256 * it;
      const int row = f >> 4;
      const int c4  = (f & 15) * 4;
      const size_t gaddr = khbase + (size_t)(t * 64 + row) * DIM + c4;
      *(float4*)&Kt[row][c4] = *(const float4*)(Kg + gaddr);
      *(float4*)&Vt[row][c4] = *(const float4*)(Vg + gaddr);
    }
    __syncthreads();

    for (int mc = 0; mc < 4; ++mc) {
      const int mbase = t * 64 + mc * 16;
      float p[16];
      float cmax = -1e30f;
#pragma unroll
      for (int mm = 0; mm < 16; ++mm) {
        float s = 0.f;
#pragma unroll
        for (int j = 0; j < 16; ++j)
          s = fmaf(q[j], Kt[mc * 16 + mm][g * 16 + j], s);
        s += __shfl_xor(s, 1);
        s += __shfl_xor(s, 2);
        s = (mbase + mm <= n) ? s : -1e30f;
        p[mm] = s;
        cmax = fmaxf(cmax, s);
      }
      const float m_new  = fmaxf(m_run, cmax);
      const float fscale = __expf(m_run - m_new);
      float psum = 0.f;
#pragma unroll
      for (int mm = 0; mm < 16; ++mm) {
        p[mm] = __expf(p[mm] - m_new);
        psum += p[mm];
      }
      l_run = l_run * fscale + psum;
#pragma unroll
      for (int j = 0; j < 16; ++j) acc[j] *= fscale;
#pragma unroll
      for (int mm = 0; mm < 16; ++mm)
#pragma unroll
        for (int j = 0; j < 16; ++j)
          acc[j] = fmaf(p[mm], Vt[mc * 16 + mm][g * 16 + j], acc[j]);
      m_run = m_new;
    }
  }

  const float inv = 1.f / l_run;
  u16* Op = O + ((size_t)(b * NSEQ + n)) * DIM + h * DH + g * 16;
#pragma unroll
  for (int j4 = 0; j4 < 4; ++j4) {
    u16x4 v;
    v[0] = f2bf(acc[j4 * 4 + 0] * inv); v[1] = f2bf(acc[j4 * 4 + 1] * inv);
    v[2] = f2bf(acc[j4 * 4 + 2] * inv); v[3] = f2bf(acc[j4 * 4 + 3] * inv);
    *(u16x4*)(Op + j4 * 4) = v;
  }
}

// ---------------------------------------------------------------------------
extern "C" void kernel_launch(void* const* d_in, const int* in_sizes, int n_in,
                              void* d_out, int out_size, void* d_ws, size_t ws_size,
                              hipStream_t stream) {
  const float* x  = (const float*)d_in[0];
  // d_in[1] = causal mask (ignored; mask is m > n analytically)
  const float* wq = (const float*)d_in[2];
  const float* bq = (const float*)d_in[3];
  const float* wk = (const float*)d_in[4];
  const float* bk = (const float*)d_in[5];
  const float* wv = (const float*)d_in[6];
  const float* bv = (const float*)d_in[7];
  const float* wo = (const float*)d_in[8];
  const float* bo = (const float*)d_in[9];
  float* out = (float*)d_out;

  char* ws = (char*)d_ws;
  u16*   Wd  = (u16*)(ws);                        //  0..8MB  4 dense bf16 W
  u16*   Xb  = (u16*)(ws + ((size_t)8  << 20));   //  8..12MB x in bf16
  float* Qb  = (float*)(ws + ((size_t)12 << 20)); // 12..20MB
  float* Kb  = (float*)(ws + ((size_t)20 << 20)); // 20..28MB
  float* Vb  = (float*)(ws + ((size_t)28 << 20)); // 28..36MB
  u16*   AOb = (u16*)(ws + ((size_t)36 << 20));   // 36..40MB attn out bf16

  // 1) densify circulant weights to dense bf16
  densify_bf16<<<dim3(4096, 1, 4), 256, 0, stream>>>(wq, wk, wv, wo, Wd);

  // 2) x -> bf16
  cvt_bf16<<<dim3((BATCH * NSEQ * DIM) / (256 * 8), 1, 1), 256, 0, stream>>>(x, Xb);

  // 3) Q/K/V projections (bf16 MFMA, fp32 out)
  gemm_bf16_nt<<<dim3(DIM / 128, (BATCH * NSEQ) / 128, 3), 256, 0, stream>>>(
      Xb, Wd, bq, bk, bv, Qb, Kb, Vb);

  // 4) causal attention (fp32 compute, bf16 out)
  attn_kernel<<<dim3(16, 16, 2), 256, 0, stream>>>(Qb, Kb, Vb, AOb);

  // 5) output projection
  gemm_bf16_nt<<<dim3(DIM / 128, (BATCH * NSEQ) / 128, 1), 256, 0, stream>>>(
      AOb, Wd + (size_t)3 * DIM * DIM, bo, bo, bo, out, out, out);
}

// Round 4
// 94.598 us; speedup vs baseline: 5.8704x; 2.7645x over previous
//
#include <hip/hip_runtime.h>
#include <hip/hip_bf16.h>

#define DIM   1024
#define NSEQ  1024
#define BATCH 2
#define NHEAD 16
#define DH    64

typedef unsigned short u16;
typedef __attribute__((ext_vector_type(8))) short  short8;
typedef __attribute__((ext_vector_type(4))) float  f32x4;
typedef __attribute__((ext_vector_type(8))) unsigned short u16x8;
typedef __attribute__((ext_vector_type(4))) unsigned short u16x4;

// log2(e) / sqrt(DH)
#define EXP_SCALE 0.18033688011112042f

__device__ __forceinline__ u16 f2bf(float f) {
  union { float f; unsigned u; } v; v.f = f;
  unsigned r = v.u + 0x7FFFu + ((v.u >> 16) & 1u);   // RNE
  return (u16)(r >> 16);
}

// ---------------------------------------------------------------------------
// Densify block-circulant weights -> bf16 dense: Wd[r][c] = w[p][q][(a-b)&7]
// ---------------------------------------------------------------------------
__global__ __launch_bounds__(256) void densify_bf16(
    const float* __restrict__ wq, const float* __restrict__ wk,
    const float* __restrict__ wv, const float* __restrict__ wo,
    u16* __restrict__ Wd) {
  const int z = blockIdx.z;
  const float* w = (z == 0) ? wq : (z == 1) ? wk : (z == 2) ? wv : wo;
  u16* out = Wd + (size_t)z * DIM * DIM;
  const int idx = blockIdx.x * 256 + threadIdx.x;
  const int r = idx >> 10, c = idx & 1023;
  const int p = r >> 3, a = r & 7;
  const int q = c >> 3, b = c & 7;
  out[idx] = f2bf(w[(p * 128 + q) * 8 + ((a - b) & 7)]);
}

// ---------------------------------------------------------------------------
// fp32 -> bf16 conversion, 8 elements/thread
// ---------------------------------------------------------------------------
__global__ __launch_bounds__(256) void cvt_bf16(
    const float* __restrict__ in, u16* __restrict__ out) {
  const int i = blockIdx.x * 256 + threadIdx.x;
  const float4 a = ((const float4*)in)[2 * i];
  const float4 b = ((const float4*)in)[2 * i + 1];
  u16x8 o;
  o[0] = f2bf(a.x); o[1] = f2bf(a.y); o[2] = f2bf(a.z); o[3] = f2bf(a.w);
  o[4] = f2bf(b.x); o[5] = f2bf(b.y); o[6] = f2bf(b.z); o[7] = f2bf(b.w);
  ((u16x8*)out)[i] = o;
}

// ---------------------------------------------------------------------------
// bf16 MFMA GEMM (NT) + bias: C[m][n] = sum_k A[m][k]*W[n][k] + bias[n]
// m97 structure: 128x128 tile, BK=32, 4 waves, global_load_lds staging.
// BFOUT=1 -> bf16 output, else fp32.
// ---------------------------------------------------------------------------
template <int BFOUT>
__global__ __launch_bounds__(256) void gemm_bf16_nt(
    const u16* __restrict__ A, const u16* __restrict__ Wbase,
    const float* __restrict__ b0, const float* __restrict__ b1,
    const float* __restrict__ b2,
    void* __restrict__ C0, void* __restrict__ C1, void* __restrict__ C2) {
  const int z = blockIdx.z;
  const u16* W      = Wbase + (size_t)z * DIM * DIM;
  const float* bias = (z == 0) ? b0 : (z == 1) ? b1 : b2;
  void* C           = (z == 0) ? C0 : (z == 1) ? C1 : C2;

  __shared__ u16 As[128 * 32];
  __shared__ u16 Bs[128 * 32];

  const int tid  = threadIdx.x;
  const int w    = tid >> 6, lane = tid & 63;
  const int mb   = blockIdx.y * 128, nb = blockIdx.x * 128;

  f32x4 acc[4][4] = {};

  const int m0 = (w >> 1) * 64, n0 = (w & 1) * 64;
  const int lr = lane & 15, lk = (lane >> 4) * 8;

  const int cb = w * 2;
  const int c0 = cb * 64 + lane;
  const int c1 = c0 + 64;
  const int row0 = c0 >> 2, kc0 = (c0 & 3) * 8;
  const int row1 = c1 >> 2, kc1 = (c1 & 3) * 8;

  for (int k0 = 0; k0 < DIM; k0 += 32) {
    __syncthreads();
    __builtin_amdgcn_global_load_lds(
        (const __attribute__((address_space(1))) void*)(A + (size_t)(mb + row0) * DIM + k0 + kc0),
        (__attribute__((address_space(3))) void*)(As + (size_t)cb * 512), 16, 0, 0);
    __builtin_amdgcn_global_load_lds(
        (const __attribute__((address_space(1))) void*)(W + (size_t)(nb + row0) * DIM + k0 + kc0),
        (__attribute__((address_space(3))) void*)(Bs + (size_t)cb * 512), 16, 0, 0);
    __builtin_amdgcn_global_load_lds(
        (const __attribute__((address_space(1))) void*)(A + (size_t)(mb + row1) * DIM + k0 + kc1),
        (__attribute__((address_space(3))) void*)(As + (size_t)(cb + 1) * 512), 16, 0, 0);
    __builtin_amdgcn_global_load_lds(
        (const __attribute__((address_space(1))) void*)(W + (size_t)(nb + row1) * DIM + k0 + kc1),
        (__attribute__((address_space(3))) void*)(Bs + (size_t)(cb + 1) * 512), 16, 0, 0);
    __syncthreads();

    short8 a[4], b[4];
#pragma unroll
    for (int mi = 0; mi < 4; ++mi)
      a[mi] = *(const short8*)&As[(m0 + mi * 16 + lr) * 32 + lk];
#pragma unroll
    for (int ni = 0; ni < 4; ++ni)
      b[ni] = *(const short8*)&Bs[(n0 + ni * 16 + lr) * 32 + lk];
#pragma unroll
    for (int mi = 0; mi < 4; ++mi)
#pragma unroll
      for (int ni = 0; ni < 4; ++ni)
        acc[mi][ni] = __builtin_amdgcn_mfma_f32_16x16x32_bf16(
            a[mi], b[ni], acc[mi][ni], 0, 0, 0);
  }

  // epilogue: C/D layout col = lane&15, row = (lane>>4)*4 + j
  const int col = lane & 15, rq = (lane >> 4) * 4;
#pragma unroll
  for (int ni = 0; ni < 4; ++ni) {
    const int gc = nb + n0 + ni * 16 + col;
    const float bv = bias[gc];
#pragma unroll
    for (int mi = 0; mi < 4; ++mi) {
      const size_t rbase = (size_t)(mb + m0 + mi * 16 + rq) * DIM + gc;
#pragma unroll
      for (int j = 0; j < 4; ++j) {
        const float v = acc[mi][ni][j] + bv;
        if (BFOUT) ((u16*)C)[rbase + (size_t)j * DIM] = f2bf(v);
        else       ((float*)C)[rbase + (size_t)j * DIM] = v;
      }
    }
  }
}

// ---------------------------------------------------------------------------
// Causal flash attention, bf16 MFMA.
// Block: 4 waves x 16 queries (64-query tile); KV tiles of 64 staged in LDS.
// Swapped QK^T: S^T acc col = lane&15 = q  ->  lane-local softmax state.
// PV as O^T = mfma(V^T_frag, P_frag): O acc col = q, row = dh.
// K: global_load_lds + pre-swizzled source.  V: reg-staged transposed.
// P: wave-private swizzled LDS tile.  All LDS frag reads <= 2-way conflict.
// ---------------------------------------------------------------------------
__global__ __launch_bounds__(256) void attn_mfma(
    const u16* __restrict__ Qg, const u16* __restrict__ Kg,
    const u16* __restrict__ Vg, u16* __restrict__ Og) {
  const int qt = 15 - blockIdx.x;          // heavy q-tiles dispatch first (LPT)
  const int h  = blockIdx.y;
  const int b  = blockIdx.z;
  const int tid = threadIdx.x;
  const int w  = tid >> 6, l = tid & 63;
  const int lr = l & 15, lg = l >> 4;      // frag row / k-group

  __shared__ u16 Klds[64 * 64];            // [key][dh]  xor-swizzled
  __shared__ u16 Vlds[64 * 64];            // [dh][key]  transposed, swizzled
  __shared__ u16 Plds[4][16 * 64];         // per-wave [q][key], swizzled

  const int q0 = qt * 64 + w * 16;
  const int qg = q0 + lr;                  // this lane's query (global row)
  const size_t base_bh = (size_t)b * NSEQ * DIM + (size_t)h * DH;

  // Q fragments: row = q (lane&15), k = dh chunk c*32 + lg*8 .. +8
  short8 qf[2];
#pragma unroll
  for (int c = 0; c < 2; ++c)
    qf[c] = *(const short8*)(Qg + base_bh + (size_t)qg * DIM + c * 32 + lg * 8);

  f32x4 acc_o[4] = {};                     // O^T: col=q(lr), row dh=d*16+lg*4+j
  float m_run = -1e30f, l_run = 0.f;

  for (int kt = 0; kt <= qt; ++kt) {
    __syncthreads();                       // previous tile fully consumed

    // --- stage K tile: linear LDS dest, pre-swizzled global source ---
#pragma unroll
    for (int i = 0; i < 2; ++i) {
      const int cb  = w * 2 + i;           // chunk block 0..7
      const int key = cb * 8 + (l >> 3);
      const int col16 = (l & 7) ^ (key & 7);
      __builtin_amdgcn_global_load_lds(
          (const __attribute__((address_space(1))) void*)
              (Kg + base_bh + (size_t)(kt * 64 + key) * DIM + col16 * 8),
          (__attribute__((address_space(3))) void*)(Klds + cb * 512), 16, 0, 0);
    }
    // --- stage V tile transposed: Vt[dh][key], swizzled ---
    {
      const int key  = (l & 31) * 2;       // key pair
      const int dblk = w * 2 + (l >> 5);   // dh block of 8
      const u16* src = Vg + base_bh + (size_t)(kt * 64 + key) * DIM + dblk * 8;
      const u16x8 v0 = *(const u16x8*)(src);
      const u16x8 v1 = *(const u16x8*)(src + DIM);
#pragma unroll
      for (int i = 0; i < 8; ++i) {
        const int dh = dblk * 8 + i;
        const unsigned pack = (unsigned)v0[i] | ((unsigned)v1[i] << 16);
        *(unsigned*)((char*)Vlds + dh * 128 + ((key * 2) ^ ((dh & 7) << 4))) = pack;
      }
    }
    __syncthreads();                       // K/V resident

    // --- QK^T: s[t16] = S^T subtile (rows=key, col=q) ---
    f32x4 s[4] = {};
#pragma unroll
    for (int t16 = 0; t16 < 4; ++t16) {
      const int row = t16 * 16 + lr;
#pragma unroll
      for (int c = 0; c < 2; ++c) {
        const int col16 = (c * 4 + lg) ^ (row & 7);
        const short8 kf = *(const short8*)((const char*)Klds + row * 128 + col16 * 16);
        s[t16] = __builtin_amdgcn_mfma_f32_16x16x32_bf16(kf, qf[c], s[t16], 0, 0, 0);
      }
    }

    // --- mask (diagonal tile only) + online softmax (lane-local q) ---
    const bool diag = (kt == qt);
    float mloc = -1e30f;
#pragma unroll
    for (int t16 = 0; t16 < 4; ++t16)
#pragma unroll
      for (int j = 0; j < 4; ++j) {
        float v = s[t16][j];
        if (diag && (kt * 64 + t16 * 16 + lg * 4 + j) > qg) v = -1e30f;
        s[t16][j] = v;
        mloc = fmaxf(mloc, v);
      }
    mloc = fmaxf(mloc, __shfl_xor(mloc, 16));
    mloc = fmaxf(mloc, __shfl_xor(mloc, 32));
    const float m_new = fmaxf(m_run, mloc);
    const float a = exp2f((m_run - m_new) * EXP_SCALE);
    float psum = 0.f;
    u16x4 pk[4];
#pragma unroll
    for (int t16 = 0; t16 < 4; ++t16)
#pragma unroll
      for (int j = 0; j < 4; ++j) {
        const float p = exp2f((s[t16][j] - m_new) * EXP_SCALE);
        psum += p;
        pk[t16][j] = f2bf(p);
      }
    psum += __shfl_xor(psum, 16);
    psum += __shfl_xor(psum, 32);
    l_run = l_run * a + psum;
    m_run = m_new;
#pragma unroll
    for (int d = 0; d < 4; ++d) acc_o[d] *= a;

    // --- P -> wave-private LDS (swizzled), then PV ---
    char* pbase = (char*)Plds[w];
#pragma unroll
    for (int t16 = 0; t16 < 4; ++t16)
      *(u16x4*)(pbase + lr * 128 + ((t16 * 32 + lg * 8) ^ ((lr & 7) << 4))) = pk[t16];

#pragma unroll
    for (int c = 0; c < 2; ++c) {
      const short8 pf = *(const short8*)
          (pbase + lr * 128 + ((c * 64 + lg * 16) ^ ((lr & 7) << 4)));
#pragma unroll
      for (int d = 0; d < 4; ++d) {
        const int dh = d * 16 + lr;
        const short8 vf = *(const short8*)
            ((const char*)Vlds + dh * 128 + ((c * 64 + lg * 16) ^ ((dh & 7) << 4)));
        acc_o[d] = __builtin_amdgcn_mfma_f32_16x16x32_bf16(vf, pf, acc_o[d], 0, 0, 0);
      }
    }
  }

  // --- epilogue: O[q][dh] = acc_o / l_run, bf16 ---
  const float inv = 1.f / l_run;
  u16* Op = Og + (size_t)(b * NSEQ + qg) * DIM + (size_t)h * DH;
#pragma unroll
  for (int d = 0; d < 4; ++d) {
    u16x4 o;
    o[0] = f2bf(acc_o[d][0] * inv); o[1] = f2bf(acc_o[d][1] * inv);
    o[2] = f2bf(acc_o[d][2] * inv); o[3] = f2bf(acc_o[d][3] * inv);
    *(u16x4*)(Op + d * 16 + lg * 4) = o;
  }
}

// ---------------------------------------------------------------------------
extern "C" void kernel_launch(void* const* d_in, const int* in_sizes, int n_in,
                              void* d_out, int out_size, void* d_ws, size_t ws_size,
                              hipStream_t stream) {
  const float* x  = (const float*)d_in[0];
  // d_in[1] = causal mask (ignored; mask is m > n analytically)
  const float* wq = (const float*)d_in[2];
  const float* bq = (const float*)d_in[3];
  const float* wk = (const float*)d_in[4];
  const float* bk = (const float*)d_in[5];
  const float* wv = (const float*)d_in[6];
  const float* bv = (const float*)d_in[7];
  const float* wo = (const float*)d_in[8];
  const float* bo = (const float*)d_in[9];

  char* ws = (char*)d_ws;
  u16* Wd  = (u16*)(ws);                       //  0..8MB  4 dense bf16 W
  u16* Xb  = (u16*)(ws + ((size_t)8  << 20));  //  8..12MB x bf16
  u16* Qb  = (u16*)(ws + ((size_t)12 << 20));  // 12..16MB Q bf16
  u16* Kb  = (u16*)(ws + ((size_t)16 << 20));  // 16..20MB K bf16
  u16* Vb  = (u16*)(ws + ((size_t)20 << 20));  // 20..24MB V bf16
  u16* AOb = (u16*)(ws + ((size_t)24 << 20));  // 24..28MB attn out bf16

  // 1) densify circulant weights to dense bf16
  densify_bf16<<<dim3(4096, 1, 4), 256, 0, stream>>>(wq, wk, wv, wo, Wd);

  // 2) x -> bf16
  cvt_bf16<<<dim3((BATCH * NSEQ * DIM) / (256 * 8), 1, 1), 256, 0, stream>>>(x, Xb);

  // 3) Q/K/V projections (bf16 MFMA, bf16 out)
  gemm_bf16_nt<1><<<dim3(DIM / 128, (BATCH * NSEQ) / 128, 3), 256, 0, stream>>>(
      Xb, Wd, bq, bk, bv, Qb, Kb, Vb);

  // 4) causal attention (bf16 MFMA, bf16 out)
  attn_mfma<<<dim3(16, 16, 2), 256, 0, stream>>>(Qb, Kb, Vb, AOb);

  // 5) output projection (fp32 out)
  gemm_bf16_nt<0><<<dim3(DIM / 128, (BATCH * NSEQ) / 128, 1), 256, 0, stream>>>(
      AOb, Wd + (size_t)3 * DIM * DIM, bo, bo, bo, d_out, d_out, d_out);
}